// Round 13
// baseline (529.629 us; speedup 1.0000x reference)
//
#include <hip/hip_runtime.h>
#include <hip/hip_bf16.h>
#include <hip/hip_fp16.h>
#include <math.h>

#define NEG_SLOPE 0.2f

typedef _Float16 half8 __attribute__((ext_vector_type(8)));
typedef _Float16 half4 __attribute__((ext_vector_type(4)));
typedef float f32x4 __attribute__((ext_vector_type(4)));

// ---------------------------------------------------------------- fused prep
// blocks [0, nbWt)  : W1/W2/W3 -> transposed hi/lo fp16 planes
// blocks [nbWt, ...): degree histogram (deg pre-zeroed)
__global__ __launch_bounds__(256) void prep_kernel(
        const float* __restrict__ W1, const float* __restrict__ W2,
        const float* __restrict__ W3,
        _Float16* __restrict__ b1h, _Float16* __restrict__ b1l,
        _Float16* __restrict__ b2h, _Float16* __restrict__ b2l,
        _Float16* __restrict__ b3h, _Float16* __restrict__ b3l,
        const int* __restrict__ ei, int E, int n, int* __restrict__ deg,
        int nbWt) {
    int b = blockIdx.x;
    if (b < nbWt) {
        int idx = b * 256 + threadIdx.x;
        const float* W; _Float16 *bh, *bl; int K, N, li;
        if (idx < 256 * 128) {
            W = W1; bh = b1h; bl = b1l; K = 128; N = 256; li = idx;
        } else if (idx < 256 * 128 + 256 * 256) {
            W = W2; bh = b2h; bl = b2l; K = 256; N = 256; li = idx - 256 * 128;
        } else if (idx < 256 * 128 + 2 * 256 * 256) {
            W = W3; bh = b3h; bl = b3l; K = 256; N = 160; li = idx - 256 * 128 - 256 * 256;
        } else return;
        int nn = li / K, k = li % K;
        float v = (nn < N) ? W[(size_t)k * N + nn] : 0.f;
        _Float16 h = (_Float16)v;
        bh[li] = h;
        bl[li] = (_Float16)(v - (float)h);
    } else {
        int e = (b - nbWt) * 256 + threadIdx.x;
        int tot = E + n;
        if (e >= tot) return;
        int d = (e < E) ? ei[E + e] : (e - E);
        atomicAdd(&deg[d], 1);
    }
}

// ---------------------------------------------------------------- scan / scatter
__global__ __launch_bounds__(1024) void scan_block(const int* __restrict__ deg,
                                                   int* __restrict__ row_off,
                                                   int* __restrict__ bsums, int n) {
    __shared__ int tmp[1024];
    int t = threadIdx.x;
    int idx = blockIdx.x * 1024 + t;
    int v = (idx < n) ? deg[idx] : 0;
    tmp[t] = v;
    __syncthreads();
    #pragma unroll
    for (int off = 1; off < 1024; off <<= 1) {
        int x = (t >= off) ? tmp[t - off] : 0;
        __syncthreads();
        tmp[t] += x;
        __syncthreads();
    }
    if (idx < n) row_off[idx] = tmp[t] - v;
    if (t == 1023) bsums[blockIdx.x] = tmp[1023];
}

__global__ __launch_bounds__(1024) void scan_add(int* __restrict__ row_off,
                                                 const int* __restrict__ bsums,
                                                 int* __restrict__ cursor,
                                                 int n, int total) {
    __shared__ int carry_s;
    int b = blockIdx.x;
    if (threadIdx.x == 0) {
        int c = 0;
        for (int i = 0; i < b; i++) c += bsums[i];
        carry_s = c;
        if (b == 0) row_off[n] = total;
    }
    __syncthreads();
    int idx = b * 1024 + threadIdx.x;
    if (idx < n) {
        int v = row_off[idx] + carry_s;
        row_off[idx] = v;
        cursor[idx] = v;
    }
}

__global__ void scatter_kernel(const int* __restrict__ ei, int E, int n,
                               int* __restrict__ cursor, int* __restrict__ csr_src) {
    int e = blockIdx.x * 256 + threadIdx.x;
    int tot = E + n;
    if (e >= tot) return;
    int s, d;
    if (e < E) { s = ei[e]; d = ei[E + e]; } else { s = d = e - E; }
    int pos = atomicAdd(&cursor[d], 1);
    csr_src[pos] = s;
}

// ---------------------------------------------------------------- MFMA GEMM
// A single-plane (fp16, or fp32 converted in staging); B split hi/lo ->
// 2-term MFMA, fp32 acc. BM=64, BN=256 (A read once), BK=32, 4 waves.
// CF: 0 = no coef epilogue, 1 = C=64 shfl coef (head = wave),
//     2 = C=40 LDS-atomic coef (heads straddle waves).
template <int NK, int CF, bool AF32>
__global__ __launch_bounds__(256) void gemm_mfma(const void* __restrict__ Ap,
                                                 const _Float16* __restrict__ Bthi,
                                                 const _Float16* __restrict__ Btlo,
                                                 _Float16* __restrict__ Ch,
                                                 const float* __restrict__ a_src,
                                                 const float* __restrict__ a_dst,
                                                 float* __restrict__ als,
                                                 float* __restrict__ ald,
                                                 int M, int N) {
    constexpr int K = NK * 32;
    __shared__ _Float16 Ah[2][2048];   // [dbuf][64 rows x 32 halves]
    __shared__ float red[64][8];       // CF==2 reduction buffer (2 KB)
    int t = threadIdx.x;
    int wave = t >> 6, lane = t & 63;
    int row0 = blockIdx.x * 64;

    auto lds_off = [](int m, int g0) -> int {
        int P = m >> 1;
        int gp = ((m & 1) << 2) | g0;
        return P * 64 + ((gp ^ (P & 7)) << 3);
    };

    // ---- staging setup
    // AF32=false: global_load_lds, linear LDS slot = tid, inverse-swizzled src
    int Pw = t >> 3;
    int gpw = (t & 7) ^ (Pw & 7);
    int m_w = 2 * Pw + (gpw >> 2);
    int g0w = gpw & 3;
    int growL = row0 + m_w; if (growL >= M) growL = M - 1;
    const _Float16* srcp16 = (const _Float16*)Ap + (size_t)growL * K + g0w * 8;

    // AF32=true: reg staging (load fp32, convert, ds_write swizzled)
    int r0 = t >> 2, g0 = t & 3;
    int off0 = lds_off(r0, g0);
    int growR = row0 + r0; if (growR >= M) growR = M - 1;
    const float* srcpf = (const float*)Ap + (size_t)growR * K + g0 * 8;
    half8 svh;

    auto stage_async = [&](int buf, int k0) {
        __builtin_amdgcn_global_load_lds(
            (const __attribute__((address_space(1))) void*)(srcp16 + k0),
            (__attribute__((address_space(3))) void*)(&Ah[buf][(size_t)wave * 512]),
            16, 0, 0);
    };
    auto stage_loadf = [&](int k0) {
        float4 v0 = *(const float4*)(srcpf + k0);
        float4 v1 = *(const float4*)(srcpf + k0 + 4);
        svh[0] = (_Float16)v0.x; svh[1] = (_Float16)v0.y;
        svh[2] = (_Float16)v0.z; svh[3] = (_Float16)v0.w;
        svh[4] = (_Float16)v1.x; svh[5] = (_Float16)v1.y;
        svh[6] = (_Float16)v1.z; svh[7] = (_Float16)v1.w;
    };
    auto stage_writef = [&](int buf) {
        *(half8*)(&Ah[buf][off0]) = svh;
    };

    const _Float16* bhp[4];
    const _Float16* blp[4];
    #pragma unroll
    for (int nf = 0; nf < 4; nf++) {
        int n = wave * 64 + nf * 16 + (lane & 15);
        bhp[nf] = Bthi + (size_t)n * K + (lane >> 4) * 8;
        blp[nf] = Btlo + (size_t)n * K + (lane >> 4) * 8;
    }

    f32x4 acc[4][4];
    #pragma unroll
    for (int i = 0; i < 4; i++)
        #pragma unroll
        for (int j = 0; j < 4; j++)
            acc[i][j] = (f32x4)0.f;

    if (AF32) {
        stage_loadf(0);
        stage_writef(0);
    } else {
        stage_async(0, 0);
    }
    __syncthreads();

    #pragma unroll
    for (int kt = 0; kt < NK; kt++) {
        int cur = kt & 1;
        int k0 = kt * 32;

        if (!AF32) {
            if (kt + 1 < NK) stage_async(cur ^ 1, (kt + 1) * 32);
        }
        half8 bh[4], bl[4];
        #pragma unroll
        for (int nf = 0; nf < 4; nf++) {
            bh[nf] = *(const half8*)(bhp[nf] + k0);
            bl[nf] = *(const half8*)(blp[nf] + k0);
        }
        if (AF32) {
            if (kt + 1 < NK) stage_loadf((kt + 1) * 32);
        }

        half8 ah[4];
        #pragma unroll
        for (int mf = 0; mf < 4; mf++) {
            int m = mf * 16 + (lane & 15);
            int off = lds_off(m, lane >> 4);
            ah[mf] = *(half8*)(&Ah[cur][off]);
        }
        #pragma unroll
        for (int mf = 0; mf < 4; mf++)
            #pragma unroll
            for (int nf = 0; nf < 4; nf++) {
                acc[mf][nf] = __builtin_amdgcn_mfma_f32_16x16x32_f16(
                    ah[mf], bh[nf], acc[mf][nf], 0, 0, 0);
                acc[mf][nf] = __builtin_amdgcn_mfma_f32_16x16x32_f16(
                    ah[mf], bl[nf], acc[mf][nf], 0, 0, 0);
            }
        if (kt + 1 < NK) {
            if (AF32) stage_writef(cur ^ 1);
            __syncthreads();
        }
    }

    // fp16 store: C/D layout col = lane&15, row = (lane>>4)*4 + q
    #pragma unroll
    for (int mf = 0; mf < 4; mf++)
        #pragma unroll
        for (int nf = 0; nf < 4; nf++) {
            int col = wave * 64 + nf * 16 + (lane & 15);
            if (col >= N) continue;
            #pragma unroll
            for (int q = 0; q < 4; q++) {
                int row = row0 + mf * 16 + (lane >> 4) * 4 + q;
                if (row < M)
                    Ch[(size_t)row * N + col] = (_Float16)acc[mf][nf][q];
            }
        }

    // ---- fused attention coefficients
    if (CF == 1) {
        // C=64: head = wave; 16-col-lane shfl reduce
        float asv[4], adv[4];
        #pragma unroll
        for (int nf = 0; nf < 4; nf++) {
            int cih = nf * 16 + (lane & 15);
            asv[nf] = a_src[wave * 64 + cih];
            adv[nf] = a_dst[wave * 64 + cih];
        }
        #pragma unroll
        for (int mf = 0; mf < 4; mf++)
            #pragma unroll
            for (int q = 0; q < 4; q++) {
                float ss = 0.f, sd = 0.f;
                #pragma unroll
                for (int nf = 0; nf < 4; nf++) {
                    float v = acc[mf][nf][q];
                    ss = fmaf(v, asv[nf], ss);
                    sd = fmaf(v, adv[nf], sd);
                }
                #pragma unroll
                for (int off = 8; off >= 1; off >>= 1) {
                    ss += __shfl_xor(ss, off, 64);
                    sd += __shfl_xor(sd, off, 64);
                }
                int row = row0 + mf * 16 + (lane >> 4) * 4 + q;
                if ((lane & 15) == 0 && row < M) {
                    als[row * 4 + wave] = ss;
                    ald[row * 4 + wave] = sd;
                }
            }
    } else if (CF == 2) {
        // C=40: heads straddle waves -> LDS atomic reduce per (row, head)
        for (int i = t; i < 64 * 8; i += 256) ((float*)red)[i] = 0.f;
        __syncthreads();
        int hd4[4]; float asv[4], adv[4]; bool ok4[4];
        #pragma unroll
        for (int nf = 0; nf < 4; nf++) {
            int col = wave * 64 + nf * 16 + (lane & 15);
            bool ok = col < 160;
            int hd = ok ? col / 40 : 0;
            int ch = ok ? col % 40 : 0;
            hd4[nf] = hd; ok4[nf] = ok;
            asv[nf] = ok ? a_src[hd * 40 + ch] : 0.f;
            adv[nf] = ok ? a_dst[hd * 40 + ch] : 0.f;
        }
        #pragma unroll
        for (int mf = 0; mf < 4; mf++)
            #pragma unroll
            for (int q = 0; q < 4; q++) {
                int rl = mf * 16 + (lane >> 4) * 4 + q;
                #pragma unroll
                for (int nf = 0; nf < 4; nf++) {
                    if (ok4[nf]) {
                        float v = acc[mf][nf][q];
                        atomicAdd(&red[rl][hd4[nf]], v * asv[nf]);
                        atomicAdd(&red[rl][4 + hd4[nf]], v * adv[nf]);
                    }
                }
            }
        __syncthreads();
        int rl = t >> 2, hd = t & 3;
        int row = row0 + rl;
        if (row < M) {
            als[row * 4 + hd] = red[rl][hd];
            ald[row * 4 + hd] = red[rl][4 + hd];
        }
    }
}

// ---------------------------------------------------------------- fused softmax + aggregation
template <int C, int MODE>
__global__ __launch_bounds__(256) void agg_kernel(const __half* __restrict__ hhp,
                                                  const float* __restrict__ als,
                                                  const float* __restrict__ ald,
                                                  const int* __restrict__ row_off,
                                                  const int* __restrict__ csr_src,
                                                  const float* __restrict__ bias,
                                                  const _Float16* __restrict__ rh,
                                                  float* __restrict__ outf,
                                                  _Float16* __restrict__ oh, int n) {
    constexpr int HC = 4 * C;          // halves per row (256 or 160)
    constexpr int LPN = HC / 8;        // lanes per node (32 or 20)
    constexpr int LPH = C / 8;         // lanes per head (8 or 5)
    const _Float16* hh = (const _Float16*)hhp;

    int t = threadIdx.x;
    int wave = t >> 6, lane = t & 63;
    int l = lane & 31;
    int node = (blockIdx.x * 4 + wave) * 2 + (lane >> 5);
    bool nact = node < n;
    bool lact = nact && (l < LPN);
    int g = (l < LPN) ? (l / LPH) : 0;

    int rs = 0, cnt = 0;
    if (lact) {
        rs = row_off[node];
        cnt = row_off[node + 1] - rs;
    }
    float aldg = lact ? ald[node * 4 + g] : 0.f;

    float acc[8] = {};
    float den = 0.f;

    if (cnt > 0) {
        int sA[8];
        float avA[8];
        #pragma unroll
        for (int q = 0; q < 8; q++) {
            int idx = q < cnt ? q : cnt - 1;
            sA[q] = csr_src[rs + idx];
        }
        #pragma unroll
        for (int q = 0; q < 8; q++) avA[q] = als[sA[q] * 4 + g];

        for (int base = 0; base < cnt; base += 8) {
            half8 hv[8];
            #pragma unroll
            for (int q = 0; q < 8; q++)
                hv[q] = *(const half8*)(hh + (size_t)sA[q] * HC + l * 8);

            int sB[8];
            float avB[8];
            if (base + 8 < cnt) {
                #pragma unroll
                for (int q = 0; q < 8; q++) {
                    int idx = base + 8 + q; if (idx >= cnt) idx = cnt - 1;
                    sB[q] = csr_src[rs + idx];
                }
                #pragma unroll
                for (int q = 0; q < 8; q++) avB[q] = als[sB[q] * 4 + g];
            }

            float ex[8];
            #pragma unroll
            for (int q = 0; q < 8; q++) {
                float lg = avA[q] + aldg;
                lg = (lg > 0.f) ? lg : NEG_SLOPE * lg;
                float e = __expf(lg);
                ex[q] = (base + q < cnt) ? e : 0.f;
                den += ex[q];
            }
            #pragma unroll
            for (int q = 0; q < 8; q++) {
                #pragma unroll
                for (int k = 0; k < 8; k++)
                    acc[k] = fmaf(ex[q], (float)hv[q][k], acc[k]);
            }
            #pragma unroll
            for (int q = 0; q < 8; q++) { sA[q] = sB[q]; avA[q] = avB[q]; }
        }
    }

    float inv = 1.f / (den + 1e-16f);
    float v[8];
    #pragma unroll
    for (int k = 0; k < 8; k++) v[k] = acc[k] * inv;

    if (MODE == 2) {
        float vs[8];
        #pragma unroll
        for (int k = 0; k < 8; k++) vs[k] = v[k];
        #pragma unroll
        for (int k2 = 1; k2 < 4; k2++) {
            #pragma unroll
            for (int k = 0; k < 8; k++)
                vs[k] += __shfl(v[k], lane + 5 * k2, 64);
        }
        if (nact && l < 5) {
            float b[8];
            *(float4*)&b[0] = *(const float4*)(bias + l * 8);
            *(float4*)&b[4] = *(const float4*)(bias + l * 8 + 4);
            float o[8];
            #pragma unroll
            for (int k = 0; k < 8; k++) o[k] = vs[k] * 0.25f + b[k];
            *(float4*)(outf + (size_t)node * C + l * 8)     = make_float4(o[0], o[1], o[2], o[3]);
            *(float4*)(outf + (size_t)node * C + l * 8 + 4) = make_float4(o[4], o[5], o[6], o[7]);
        }
    } else {
        if (lact) {
            float b[8];
            *(float4*)&b[0] = *(const float4*)(bias + l * 8);
            *(float4*)&b[4] = *(const float4*)(bias + l * 8 + 4);
            float o[8];
            #pragma unroll
            for (int k = 0; k < 8; k++) o[k] = v[k] + b[k];
            if (MODE == 1) {
                size_t ridx = (size_t)node * HC + l * 8;
                half8 r_h = *(const half8*)(rh + ridx);
                #pragma unroll
                for (int k = 0; k < 8; k++) o[k] += (float)r_h[k];
            }
            #pragma unroll
            for (int k = 0; k < 8; k++) o[k] = (o[k] > 0.f) ? o[k] : expm1f(o[k]);
            half8 hv8;
            #pragma unroll
            for (int k = 0; k < 8; k++) hv8[k] = (_Float16)o[k];
            *(half8*)(oh + (size_t)node * HC + l * 8) = hv8;
        }
    }
}

// ---------------------------------------------------------------- launch
extern "C" void kernel_launch(void* const* d_in, const int* in_sizes, int n_in,
                              void* d_out, int out_size, void* d_ws, size_t ws_size,
                              hipStream_t stream) {
    const float* x   = (const float*)d_in[0];
    const int*   ei  = (const int*)d_in[1];
    const float* W1  = (const float*)d_in[2];
    const float* a1s = (const float*)d_in[3];
    const float* a1d = (const float*)d_in[4];
    const float* b1  = (const float*)d_in[5];
    const float* W2  = (const float*)d_in[6];
    const float* a2s = (const float*)d_in[7];
    const float* a2d = (const float*)d_in[8];
    const float* b2  = (const float*)d_in[9];
    const float* W3  = (const float*)d_in[10];
    const float* a3s = (const float*)d_in[11];
    const float* a3d = (const float*)d_in[12];
    const float* b3  = (const float*)d_in[13];
    float* out = (float*)d_out;

    int N = in_sizes[0] / 128;
    int E = in_sizes[1] / 2;

    char* ws = (char*)d_ws;
    size_t off = 0;
    auto alloc = [&](size_t bytes) -> void* {
        void* p = ws + off;
        off += (bytes + 255) & ~(size_t)255;
        return p;
    };
    _Float16* hhalf = (_Float16*)alloc((size_t)N * 256 * 2);
    _Float16* pA    = (_Float16*)alloc((size_t)N * 256 * 2);   // x2 fp16
    _Float16* pB    = (_Float16*)alloc((size_t)N * 256 * 2);   // x1 fp16
    float*    als   = (float*)alloc((size_t)N * 4 * 4);
    float*    ald   = (float*)alloc((size_t)N * 4 * 4);
    _Float16* bt1h  = (_Float16*)alloc(256 * 128 * 2);
    _Float16* bt1l  = (_Float16*)alloc(256 * 128 * 2);
    _Float16* bt2h  = (_Float16*)alloc(256 * 256 * 2);
    _Float16* bt2l  = (_Float16*)alloc(256 * 256 * 2);
    _Float16* bt3h  = (_Float16*)alloc(256 * 256 * 2);
    _Float16* bt3l  = (_Float16*)alloc(256 * 256 * 2);
    int* deg     = (int*)alloc((size_t)N * 4);
    int* row_off = (int*)alloc((size_t)(N + 1) * 4);
    int* cursor  = (int*)alloc((size_t)N * 4);
    int* csr     = (int*)alloc((size_t)(E + N) * 4);
    int* bsums   = (int*)alloc(1024 * 4);

    int tot = E + N;
    int nb = (N + 1023) / 1024;
    int wtot = 256 * 128 + 2 * 256 * 256;
    int nbWt = (wtot + 255) / 256;
    int nbDeg = (tot + 255) / 256;

    hipMemsetAsync(deg, 0, (size_t)N * 4, stream);
    prep_kernel<<<nbWt + nbDeg, 256, 0, stream>>>(
        W1, W2, W3, bt1h, bt1l, bt2h, bt2l, bt3h, bt3l,
        ei, E, N, deg, nbWt);
    scan_block<<<nb, 1024, 0, stream>>>(deg, row_off, bsums, N);
    scan_add<<<nb, 1024, 0, stream>>>(row_off, bsums, cursor, N, tot);
    scatter_kernel<<<(tot + 255) / 256, 256, 0, stream>>>(ei, E, N, cursor, csr);

    int pairs = (N + 1) / 2;
    int aggBlocks = (pairs + 3) / 4; // agg: 4 waves/block, 2 nodes/wave
    dim3 blk(256);
    dim3 ggrid((N + 63) / 64);       // GEMM: BM=64, BN=256 full width

    // layer 1: h = x @ W1 (K=128, fp32 A converted in staging); coef fused
    gemm_mfma<4, 1, true><<<ggrid, blk, 0, stream>>>(x, bt1h, bt1l, hhalf,
                                                     a1s, a1d, als, ald, N, 256);
    agg_kernel<64, 0><<<aggBlocks, blk, 0, stream>>>((const __half*)hhalf, als, ald,
        row_off, csr, b1, nullptr, nullptr, pB, N);

    // layer 2: h = x1 @ W2 (K=256); coef fused; residual = x1 (fp16)
    gemm_mfma<8, 1, false><<<ggrid, blk, 0, stream>>>(pB, bt2h, bt2l, hhalf,
                                                      a2s, a2d, als, ald, N, 256);
    agg_kernel<64, 1><<<aggBlocks, blk, 0, stream>>>((const __half*)hhalf, als, ald,
        row_off, csr, b2, pB, nullptr, pA, N);

    // layer 3: h = x2 @ W3 (K=256, N=160); coef fused via LDS reduce
    gemm_mfma<8, 2, false><<<ggrid, blk, 0, stream>>>(pA, bt3h, bt3l, hhalf,
                                                      a3s, a3d, als, ald, N, 160);
    agg_kernel<40, 2><<<aggBlocks, blk, 0, stream>>>((const __half*)hhalf, als, ald,
        row_off, csr, b3, nullptr, out, nullptr, N);
}

// Round 14
// 432.556 us; speedup vs baseline: 1.2244x; 1.2244x over previous
//
#include <hip/hip_runtime.h>
#include <hip/hip_bf16.h>
#include <hip/hip_fp16.h>
#include <math.h>

#define NEG_SLOPE 0.2f

typedef _Float16 half8 __attribute__((ext_vector_type(8)));
typedef _Float16 half4 __attribute__((ext_vector_type(4)));
typedef float f32x4 __attribute__((ext_vector_type(4)));

// ---------------------------------------------------------------- fused prep
// blocks [0, nbWt)  : W1/W2/W3 -> transposed hi/lo fp16 planes
// blocks [nbWt, ...): degree histogram (deg pre-zeroed)
__global__ __launch_bounds__(256) void prep_kernel(
        const float* __restrict__ W1, const float* __restrict__ W2,
        const float* __restrict__ W3,
        _Float16* __restrict__ b1h, _Float16* __restrict__ b1l,
        _Float16* __restrict__ b2h, _Float16* __restrict__ b2l,
        _Float16* __restrict__ b3h, _Float16* __restrict__ b3l,
        const int* __restrict__ ei, int E, int n, int* __restrict__ deg,
        int nbWt) {
    int b = blockIdx.x;
    if (b < nbWt) {
        int idx = b * 256 + threadIdx.x;
        const float* W; _Float16 *bh, *bl; int K, N, li;
        if (idx < 256 * 128) {
            W = W1; bh = b1h; bl = b1l; K = 128; N = 256; li = idx;
        } else if (idx < 256 * 128 + 256 * 256) {
            W = W2; bh = b2h; bl = b2l; K = 256; N = 256; li = idx - 256 * 128;
        } else if (idx < 256 * 128 + 2 * 256 * 256) {
            W = W3; bh = b3h; bl = b3l; K = 256; N = 160; li = idx - 256 * 128 - 256 * 256;
        } else return;
        int nn = li / K, k = li % K;
        float v = (nn < N) ? W[(size_t)k * N + nn] : 0.f;
        _Float16 h = (_Float16)v;
        bh[li] = h;
        bl[li] = (_Float16)(v - (float)h);
    } else {
        int e = (b - nbWt) * 256 + threadIdx.x;
        int tot = E + n;
        if (e >= tot) return;
        int d = (e < E) ? ei[E + e] : (e - E);
        atomicAdd(&deg[d], 1);
    }
}

// ---------------------------------------------------------------- scan / scatter
__global__ __launch_bounds__(1024) void scan_block(const int* __restrict__ deg,
                                                   int* __restrict__ row_off,
                                                   int* __restrict__ bsums, int n) {
    __shared__ int tmp[1024];
    int t = threadIdx.x;
    int idx = blockIdx.x * 1024 + t;
    int v = (idx < n) ? deg[idx] : 0;
    tmp[t] = v;
    __syncthreads();
    #pragma unroll
    for (int off = 1; off < 1024; off <<= 1) {
        int x = (t >= off) ? tmp[t - off] : 0;
        __syncthreads();
        tmp[t] += x;
        __syncthreads();
    }
    if (idx < n) row_off[idx] = tmp[t] - v;
    if (t == 1023) bsums[blockIdx.x] = tmp[1023];
}

__global__ __launch_bounds__(1024) void scan_add(int* __restrict__ row_off,
                                                 const int* __restrict__ bsums,
                                                 int* __restrict__ cursor,
                                                 int n, int total) {
    __shared__ int carry_s;
    int b = blockIdx.x;
    if (threadIdx.x == 0) {
        int c = 0;
        for (int i = 0; i < b; i++) c += bsums[i];
        carry_s = c;
        if (b == 0) row_off[n] = total;
    }
    __syncthreads();
    int idx = b * 1024 + threadIdx.x;
    if (idx < n) {
        int v = row_off[idx] + carry_s;
        row_off[idx] = v;
        cursor[idx] = v;
    }
}

__global__ void scatter_kernel(const int* __restrict__ ei, int E, int n,
                               int* __restrict__ cursor, int* __restrict__ csr_src) {
    int e = blockIdx.x * 256 + threadIdx.x;
    int tot = E + n;
    if (e >= tot) return;
    int s, d;
    if (e < E) { s = ei[e]; d = ei[E + e]; } else { s = d = e - E; }
    int pos = atomicAdd(&cursor[d], 1);
    csr_src[pos] = s;
}

// ---------------------------------------------------------------- MFMA GEMM
// A single-plane (fp16, or fp32 converted in staging); B split hi/lo ->
// 2-term MFMA, fp32 acc. BM=64, BN=256 (A read once), BK=32, 4 waves.
// CF: 0 = no coef epilogue, 1 = C=64 shfl coef (head = wave).
template <int NK, int CF, bool AF32>
__global__ __launch_bounds__(256) void gemm_mfma(const void* __restrict__ Ap,
                                                 const _Float16* __restrict__ Bthi,
                                                 const _Float16* __restrict__ Btlo,
                                                 _Float16* __restrict__ Ch,
                                                 const float* __restrict__ a_src,
                                                 const float* __restrict__ a_dst,
                                                 float* __restrict__ als,
                                                 float* __restrict__ ald,
                                                 int M, int N) {
    constexpr int K = NK * 32;
    __shared__ _Float16 Ah[2][2048];   // [dbuf][64 rows x 32 halves]
    int t = threadIdx.x;
    int wave = t >> 6, lane = t & 63;
    int row0 = blockIdx.x * 64;

    auto lds_off = [](int m, int g0) -> int {
        int P = m >> 1;
        int gp = ((m & 1) << 2) | g0;
        return P * 64 + ((gp ^ (P & 7)) << 3);
    };

    // AF32=false: global_load_lds, linear LDS slot = tid, inverse-swizzled src
    int Pw = t >> 3;
    int gpw = (t & 7) ^ (Pw & 7);
    int m_w = 2 * Pw + (gpw >> 2);
    int g0w = gpw & 3;
    int growL = row0 + m_w; if (growL >= M) growL = M - 1;
    const _Float16* srcp16 = (const _Float16*)Ap + (size_t)growL * K + g0w * 8;

    // AF32=true: reg staging (load fp32, convert, ds_write swizzled)
    int r0 = t >> 2, g0 = t & 3;
    int off0 = lds_off(r0, g0);
    int growR = row0 + r0; if (growR >= M) growR = M - 1;
    const float* srcpf = (const float*)Ap + (size_t)growR * K + g0 * 8;
    half8 svh;

    auto stage_async = [&](int buf, int k0) {
        __builtin_amdgcn_global_load_lds(
            (const __attribute__((address_space(1))) void*)(srcp16 + k0),
            (__attribute__((address_space(3))) void*)(&Ah[buf][(size_t)wave * 512]),
            16, 0, 0);
    };
    auto stage_loadf = [&](int k0) {
        float4 v0 = *(const float4*)(srcpf + k0);
        float4 v1 = *(const float4*)(srcpf + k0 + 4);
        svh[0] = (_Float16)v0.x; svh[1] = (_Float16)v0.y;
        svh[2] = (_Float16)v0.z; svh[3] = (_Float16)v0.w;
        svh[4] = (_Float16)v1.x; svh[5] = (_Float16)v1.y;
        svh[6] = (_Float16)v1.z; svh[7] = (_Float16)v1.w;
    };
    auto stage_writef = [&](int buf) {
        *(half8*)(&Ah[buf][off0]) = svh;
    };

    const _Float16* bhp[4];
    const _Float16* blp[4];
    #pragma unroll
    for (int nf = 0; nf < 4; nf++) {
        int n = wave * 64 + nf * 16 + (lane & 15);
        bhp[nf] = Bthi + (size_t)n * K + (lane >> 4) * 8;
        blp[nf] = Btlo + (size_t)n * K + (lane >> 4) * 8;
    }

    f32x4 acc[4][4];
    #pragma unroll
    for (int i = 0; i < 4; i++)
        #pragma unroll
        for (int j = 0; j < 4; j++)
            acc[i][j] = (f32x4)0.f;

    if (AF32) {
        stage_loadf(0);
        stage_writef(0);
    } else {
        stage_async(0, 0);
    }
    __syncthreads();

    #pragma unroll
    for (int kt = 0; kt < NK; kt++) {
        int cur = kt & 1;
        int k0 = kt * 32;

        if (!AF32) {
            if (kt + 1 < NK) stage_async(cur ^ 1, (kt + 1) * 32);
        }
        half8 bh[4], bl[4];
        #pragma unroll
        for (int nf = 0; nf < 4; nf++) {
            bh[nf] = *(const half8*)(bhp[nf] + k0);
            bl[nf] = *(const half8*)(blp[nf] + k0);
        }
        if (AF32) {
            if (kt + 1 < NK) stage_loadf((kt + 1) * 32);
        }

        half8 ah[4];
        #pragma unroll
        for (int mf = 0; mf < 4; mf++) {
            int m = mf * 16 + (lane & 15);
            int off = lds_off(m, lane >> 4);
            ah[mf] = *(half8*)(&Ah[cur][off]);
        }
        #pragma unroll
        for (int mf = 0; mf < 4; mf++)
            #pragma unroll
            for (int nf = 0; nf < 4; nf++) {
                acc[mf][nf] = __builtin_amdgcn_mfma_f32_16x16x32_f16(
                    ah[mf], bh[nf], acc[mf][nf], 0, 0, 0);
                acc[mf][nf] = __builtin_amdgcn_mfma_f32_16x16x32_f16(
                    ah[mf], bl[nf], acc[mf][nf], 0, 0, 0);
            }
        if (kt + 1 < NK) {
            if (AF32) stage_writef(cur ^ 1);
            __syncthreads();
        }
    }

    // fp16 store: C/D layout col = lane&15, row = (lane>>4)*4 + q
    #pragma unroll
    for (int mf = 0; mf < 4; mf++)
        #pragma unroll
        for (int nf = 0; nf < 4; nf++) {
            int col = wave * 64 + nf * 16 + (lane & 15);
            if (col >= N) continue;
            #pragma unroll
            for (int q = 0; q < 4; q++) {
                int row = row0 + mf * 16 + (lane >> 4) * 4 + q;
                if (row < M)
                    Ch[(size_t)row * N + col] = (_Float16)acc[mf][nf][q];
            }
        }

    // fused attention coefficients (C=64 layers): head = wave
    if (CF == 1) {
        float asv[4], adv[4];
        #pragma unroll
        for (int nf = 0; nf < 4; nf++) {
            int cih = nf * 16 + (lane & 15);
            asv[nf] = a_src[wave * 64 + cih];
            adv[nf] = a_dst[wave * 64 + cih];
        }
        #pragma unroll
        for (int mf = 0; mf < 4; mf++)
            #pragma unroll
            for (int q = 0; q < 4; q++) {
                float ss = 0.f, sd = 0.f;
                #pragma unroll
                for (int nf = 0; nf < 4; nf++) {
                    float v = acc[mf][nf][q];
                    ss = fmaf(v, asv[nf], ss);
                    sd = fmaf(v, adv[nf], sd);
                }
                #pragma unroll
                for (int off = 8; off >= 1; off >>= 1) {
                    ss += __shfl_xor(ss, off, 64);
                    sd += __shfl_xor(sd, off, 64);
                }
                int row = row0 + mf * 16 + (lane >> 4) * 4 + q;
                if ((lane & 15) == 0 && row < M) {
                    als[row * 4 + wave] = ss;
                    ald[row * 4 + wave] = sd;
                }
            }
    }
}

// ---------------------------------------------------------------- attention coefs (layer 3, fp16 h)
template <int C>
__global__ __launch_bounds__(256) void coef_kernel(const _Float16* __restrict__ h,
                                                   const float* __restrict__ a_src,
                                                   const float* __restrict__ a_dst,
                                                   float* __restrict__ als,
                                                   float* __restrict__ ald, int n) {
    int wave = threadIdx.x >> 6;
    int lane = threadIdx.x & 63;
    int node = blockIdx.x * 4 + wave;
    if (node >= n) return;
    const _Float16* hr = h + (size_t)node * (4 * C);
    float ps[4], pd[4];
    #pragma unroll
    for (int hh = 0; hh < 4; hh++) {
        float hv = (lane < C) ? (float)hr[hh * C + lane] : 0.f;
        float as_ = (lane < C) ? a_src[hh * C + lane] : 0.f;
        float ad_ = (lane < C) ? a_dst[hh * C + lane] : 0.f;
        ps[hh] = hv * as_;
        pd[hh] = hv * ad_;
    }
    #pragma unroll
    for (int off = 32; off >= 1; off >>= 1) {
        #pragma unroll
        for (int hh = 0; hh < 4; hh++) {
            ps[hh] += __shfl_xor(ps[hh], off, 64);
            pd[hh] += __shfl_xor(pd[hh], off, 64);
        }
    }
    if (lane == 0) {
        #pragma unroll
        for (int hh = 0; hh < 4; hh++) {
            als[node * 4 + hh] = ps[hh];
            ald[node * 4 + hh] = pd[hh];
        }
    }
}

// ---------------------------------------------------------------- fused softmax + aggregation
template <int C, int MODE>
__global__ __launch_bounds__(256) void agg_kernel(const __half* __restrict__ hhp,
                                                  const float* __restrict__ als,
                                                  const float* __restrict__ ald,
                                                  const int* __restrict__ row_off,
                                                  const int* __restrict__ csr_src,
                                                  const float* __restrict__ bias,
                                                  const _Float16* __restrict__ rh,
                                                  float* __restrict__ outf,
                                                  _Float16* __restrict__ oh, int n) {
    constexpr int HC = 4 * C;          // halves per row (256 or 160)
    constexpr int LPN = HC / 8;        // lanes per node (32 or 20)
    constexpr int LPH = C / 8;         // lanes per head (8 or 5)
    const _Float16* hh = (const _Float16*)hhp;

    int t = threadIdx.x;
    int wave = t >> 6, lane = t & 63;
    int l = lane & 31;
    int node = (blockIdx.x * 4 + wave) * 2 + (lane >> 5);
    bool nact = node < n;
    bool lact = nact && (l < LPN);
    int g = (l < LPN) ? (l / LPH) : 0;

    int rs = 0, cnt = 0;
    if (lact) {
        rs = row_off[node];
        cnt = row_off[node + 1] - rs;
    }
    float aldg = lact ? ald[node * 4 + g] : 0.f;

    float acc[8] = {};
    float den = 0.f;

    if (cnt > 0) {
        int sA[8];
        float avA[8];
        #pragma unroll
        for (int q = 0; q < 8; q++) {
            int idx = q < cnt ? q : cnt - 1;
            sA[q] = csr_src[rs + idx];
        }
        #pragma unroll
        for (int q = 0; q < 8; q++) avA[q] = als[sA[q] * 4 + g];

        for (int base = 0; base < cnt; base += 8) {
            half8 hv[8];
            #pragma unroll
            for (int q = 0; q < 8; q++)
                hv[q] = *(const half8*)(hh + (size_t)sA[q] * HC + l * 8);

            int sB[8];
            float avB[8];
            if (base + 8 < cnt) {
                #pragma unroll
                for (int q = 0; q < 8; q++) {
                    int idx = base + 8 + q; if (idx >= cnt) idx = cnt - 1;
                    sB[q] = csr_src[rs + idx];
                }
                #pragma unroll
                for (int q = 0; q < 8; q++) avB[q] = als[sB[q] * 4 + g];
            }

            float ex[8];
            #pragma unroll
            for (int q = 0; q < 8; q++) {
                float lg = avA[q] + aldg;
                lg = (lg > 0.f) ? lg : NEG_SLOPE * lg;
                float e = __expf(lg);
                ex[q] = (base + q < cnt) ? e : 0.f;
                den += ex[q];
            }
            #pragma unroll
            for (int q = 0; q < 8; q++) {
                #pragma unroll
                for (int k = 0; k < 8; k++)
                    acc[k] = fmaf(ex[q], (float)hv[q][k], acc[k]);
            }
            #pragma unroll
            for (int q = 0; q < 8; q++) { sA[q] = sB[q]; avA[q] = avB[q]; }
        }
    }

    float inv = 1.f / (den + 1e-16f);
    float v[8];
    #pragma unroll
    for (int k = 0; k < 8; k++) v[k] = acc[k] * inv;

    if (MODE == 2) {
        float vs[8];
        #pragma unroll
        for (int k = 0; k < 8; k++) vs[k] = v[k];
        #pragma unroll
        for (int k2 = 1; k2 < 4; k2++) {
            #pragma unroll
            for (int k = 0; k < 8; k++)
                vs[k] += __shfl(v[k], lane + 5 * k2, 64);
        }
        if (nact && l < 5) {
            float b[8];
            *(float4*)&b[0] = *(const float4*)(bias + l * 8);
            *(float4*)&b[4] = *(const float4*)(bias + l * 8 + 4);
            float o[8];
            #pragma unroll
            for (int k = 0; k < 8; k++) o[k] = vs[k] * 0.25f + b[k];
            *(float4*)(outf + (size_t)node * C + l * 8)     = make_float4(o[0], o[1], o[2], o[3]);
            *(float4*)(outf + (size_t)node * C + l * 8 + 4) = make_float4(o[4], o[5], o[6], o[7]);
        }
    } else {
        if (lact) {
            float b[8];
            *(float4*)&b[0] = *(const float4*)(bias + l * 8);
            *(float4*)&b[4] = *(const float4*)(bias + l * 8 + 4);
            float o[8];
            #pragma unroll
            for (int k = 0; k < 8; k++) o[k] = v[k] + b[k];
            if (MODE == 1) {
                size_t ridx = (size_t)node * HC + l * 8;
                half8 r_h = *(const half8*)(rh + ridx);
                #pragma unroll
                for (int k = 0; k < 8; k++) o[k] += (float)r_h[k];
            }
            #pragma unroll
            for (int k = 0; k < 8; k++) o[k] = (o[k] > 0.f) ? o[k] : expm1f(o[k]);
            half8 hv8;
            #pragma unroll
            for (int k = 0; k < 8; k++) hv8[k] = (_Float16)o[k];
            *(half8*)(oh + (size_t)node * HC + l * 8) = hv8;
        }
    }
}

// ---------------------------------------------------------------- launch
extern "C" void kernel_launch(void* const* d_in, const int* in_sizes, int n_in,
                              void* d_out, int out_size, void* d_ws, size_t ws_size,
                              hipStream_t stream) {
    const float* x   = (const float*)d_in[0];
    const int*   ei  = (const int*)d_in[1];
    const float* W1  = (const float*)d_in[2];
    const float* a1s = (const float*)d_in[3];
    const float* a1d = (const float*)d_in[4];
    const float* b1  = (const float*)d_in[5];
    const float* W2  = (const float*)d_in[6];
    const float* a2s = (const float*)d_in[7];
    const float* a2d = (const float*)d_in[8];
    const float* b2  = (const float*)d_in[9];
    const float* W3  = (const float*)d_in[10];
    const float* a3s = (const float*)d_in[11];
    const float* a3d = (const float*)d_in[12];
    const float* b3  = (const float*)d_in[13];
    float* out = (float*)d_out;

    int N = in_sizes[0] / 128;
    int E = in_sizes[1] / 2;

    char* ws = (char*)d_ws;
    size_t off = 0;
    auto alloc = [&](size_t bytes) -> void* {
        void* p = ws + off;
        off += (bytes + 255) & ~(size_t)255;
        return p;
    };
    _Float16* hhalf = (_Float16*)alloc((size_t)N * 256 * 2);
    _Float16* pA    = (_Float16*)alloc((size_t)N * 256 * 2);   // x2 fp16
    _Float16* pB    = (_Float16*)alloc((size_t)N * 256 * 2);   // x1 fp16
    float*    als   = (float*)alloc((size_t)N * 4 * 4);
    float*    ald   = (float*)alloc((size_t)N * 4 * 4);
    _Float16* bt1h  = (_Float16*)alloc(256 * 128 * 2);
    _Float16* bt1l  = (_Float16*)alloc(256 * 128 * 2);
    _Float16* bt2h  = (_Float16*)alloc(256 * 256 * 2);
    _Float16* bt2l  = (_Float16*)alloc(256 * 256 * 2);
    _Float16* bt3h  = (_Float16*)alloc(256 * 256 * 2);
    _Float16* bt3l  = (_Float16*)alloc(256 * 256 * 2);
    int* deg     = (int*)alloc((size_t)N * 4);
    int* row_off = (int*)alloc((size_t)(N + 1) * 4);
    int* cursor  = (int*)alloc((size_t)N * 4);
    int* csr     = (int*)alloc((size_t)(E + N) * 4);
    int* bsums   = (int*)alloc(1024 * 4);

    int tot = E + N;
    int nb = (N + 1023) / 1024;
    int wtot = 256 * 128 + 2 * 256 * 256;
    int nbWt = (wtot + 255) / 256;
    int nbDeg = (tot + 255) / 256;

    hipMemsetAsync(deg, 0, (size_t)N * 4, stream);
    prep_kernel<<<nbWt + nbDeg, 256, 0, stream>>>(
        W1, W2, W3, bt1h, bt1l, bt2h, bt2l, bt3h, bt3l,
        ei, E, N, deg, nbWt);
    scan_block<<<nb, 1024, 0, stream>>>(deg, row_off, bsums, N);
    scan_add<<<nb, 1024, 0, stream>>>(row_off, bsums, cursor, N, tot);
    scatter_kernel<<<(tot + 255) / 256, 256, 0, stream>>>(ei, E, N, cursor, csr);

    int nodeBlocks4 = (N + 3) / 4;   // coef: 4 nodes/block
    int pairs = (N + 1) / 2;
    int aggBlocks = (pairs + 3) / 4; // agg: 4 waves/block, 2 nodes/wave
    dim3 blk(256);
    dim3 ggrid((N + 63) / 64);       // GEMM: BM=64, BN=256 full width

    // layer 1: h = x @ W1 (K=128, fp32 A converted in staging); coef fused
    gemm_mfma<4, 1, true><<<ggrid, blk, 0, stream>>>(x, bt1h, bt1l, hhalf,
                                                     a1s, a1d, als, ald, N, 256);
    agg_kernel<64, 0><<<aggBlocks, blk, 0, stream>>>((const __half*)hhalf, als, ald,
        row_off, csr, b1, nullptr, nullptr, pB, N);

    // layer 2: h = x1 @ W2 (K=256); coef fused; residual = x1 (fp16)
    gemm_mfma<8, 1, false><<<ggrid, blk, 0, stream>>>(pB, bt2h, bt2l, hhalf,
                                                      a2s, a2d, als, ald, N, 256);
    agg_kernel<64, 1><<<aggBlocks, blk, 0, stream>>>((const __half*)hhalf, als, ald,
        row_off, csr, b2, pB, nullptr, pA, N);

    // layer 3: h = x2 @ W3 (K=256, N=160); coef from fp16 shadow (separate pass)
    gemm_mfma<8, 0, false><<<ggrid, blk, 0, stream>>>(pA, bt3h, bt3l, hhalf,
                                                      nullptr, nullptr, nullptr, nullptr, N, 160);
    coef_kernel<40><<<nodeBlocks4, blk, 0, stream>>>(hhalf, a3s, a3d, als, ald, N);
    agg_kernel<40, 2><<<aggBlocks, blk, 0, stream>>>((const __half*)hhalf, als, ald,
        row_off, csr, b3, nullptr, out, nullptr, N);
}